// Round 1
// baseline (311.555 us; speedup 1.0000x reference)
//
#include <hip/hip_runtime.h>
#include <hip/hip_bf16.h>
#include <stdint.h>

#define NROWS 32768
#define HDIM  1024
#define CNB   8
#define DCS   128
#define KCB   512

typedef short bf16x8 __attribute__((ext_vector_type(8)));
typedef float f32x4 __attribute__((ext_vector_type(4)));

__device__ __forceinline__ unsigned f2bfu(float x) {
  union { float f; unsigned u; } v; v.f = x;
  return (v.u + 0x7fffu + ((v.u >> 16) & 1u)) >> 16;
}

// ---- prep: codesT[c][k][d] = codes[c][d][k]; cn2 = sum_d codes^2; rcn = rsqrt(cn2); zero loss slot
__global__ __launch_bounds__(256) void prep_kernel(
    const float* __restrict__ codes, float* __restrict__ codesT,
    float* __restrict__ cn2, float* __restrict__ rcn, float* __restrict__ loss_slot) {
  const int c = blockIdx.y;
  const int k0 = blockIdx.x * 64;
  const int t = threadIdx.x;
  const int kl = t & 63;
  const int dq = t >> 6;
  const int k = k0 + kl;
  const float* src = codes + (size_t)c * DCS * KCB + k;
  float* dst = codesT + ((size_t)c * KCB + k) * DCS;
  float acc = 0.f;
#pragma unroll
  for (int i = 0; i < 32; ++i) {
    int d = dq * 32 + i;
    float v = src[(size_t)d * KCB];
    acc += v * v;
    dst[d] = v;
  }
  __shared__ float red[256];
  red[t] = acc;
  __syncthreads();
  if (t < 64) {
    float s = red[t] + red[t + 64] + red[t + 128] + red[t + 192];
    cn2[c * KCB + k0 + t] = s;
    rcn[c * KCB + k0 + t] = rsqrtf(s);
  }
  if (blockIdx.x == 0 && c == 0 && t == 0) *loss_slot = 0.f;
}

// ---- main: per block: 64 rows x 1 codebook. 4 waves, 16 rows each.
__global__ __launch_bounds__(256, 4) void vq_kernel(
    const float* __restrict__ hidden, const float* __restrict__ gumbel,
    const float* __restrict__ codesT, const float* __restrict__ cn2g,
    const float* __restrict__ rcn, float* __restrict__ out, float* __restrict__ loss_slot) {
  const int c = blockIdx.y;
  const int nb = blockIdx.x * 64;
  const int tid = threadIdx.x;
  const int w = tid >> 6;
  const int l = tid & 63;
  const int l15 = l & 15;
  const int l4 = l >> 4;

  __shared__ short ldsB[128 * 128];   // 32 KB, XOR-swizzled [k][d] bf16 chunk
  __shared__ float wloss[4];

  // --- load h rows (A rows = l&15), fp32 row norm, pre-scale by 1/||h||, cast bf16
  const int nrow = nb + w * 16 + l15;
  const float* hp = hidden + (size_t)nrow * HDIM + c * DCS + l4 * 8;
  float hv[4][8];
  float hn2 = 0.f;
#pragma unroll
  for (int s = 0; s < 4; ++s) {
    f32x4 p0 = *(const f32x4*)(hp + s * 32);
    f32x4 p1 = *(const f32x4*)(hp + s * 32 + 4);
#pragma unroll
    for (int j = 0; j < 4; ++j) { hv[s][j] = p0[j]; hv[s][4 + j] = p1[j]; }
#pragma unroll
    for (int j = 0; j < 8; ++j) hn2 += hv[s][j] * hv[s][j];
  }
  hn2 += __shfl_xor(hn2, 16);
  hn2 += __shfl_xor(hn2, 32);            // all lanes: full ||h||^2 of row (l&15)
  const float hnorm = sqrtf(hn2);
  const float rh = hnorm > 0.f ? 1.0f / hnorm : 0.f;
  bf16x8 afr[4];
#pragma unroll
  for (int s = 0; s < 4; ++s)
#pragma unroll
    for (int j = 0; j < 8; ++j) afr[s][j] = (short)f2bfu(hv[s][j] * rh);

  // --- gumbel row pointers (D rows = (l>>4)*4 + reg)
  const float* gp0 = gumbel + ((size_t)(nb + w * 16 + l4 * 4) * CNB + c) * KCB + l15;
  const float* gp1 = gp0 + (size_t)CNB * KCB;
  const float* gp2 = gp1 + (size_t)CNB * KCB;
  const float* gp3 = gp2 + (size_t)CNB * KCB;
  const float* rcp = rcn + c * KCB + l15;

  float bs0 = -3.4e38f, bs1 = -3.4e38f, bs2 = -3.4e38f, bs3 = -3.4e38f;
  int   bk0 = 0, bk1 = 0, bk2 = 0, bk3 = 0;     // candidate id = (kc>>4)+t
  float ba0 = 0.f, ba1 = 0.f, ba2 = 0.f, ba3 = 0.f; // winning scaled dot

  const unsigned swz = (unsigned)(l15 & 7) << 4;

#pragma unroll 1
  for (int kc = 0; kc < KCB; kc += 128) {
    __syncthreads();   // prior-chunk reads done before restage
    {
      const float* ct = codesT + ((size_t)c * KCB + kc) * DCS;
      const int kr = tid >> 5;
      const int d4 = (tid & 31) * 4;
#pragma unroll
      for (int p = 0; p < 16; ++p) {
        const int k = kr + 8 * p;
        f32x4 v = *(const f32x4*)(ct + (size_t)k * DCS + d4);
        unsigned lo = f2bfu(v[0]) | (f2bfu(v[1]) << 16);
        unsigned hi = f2bfu(v[2]) | (f2bfu(v[3]) << 16);
        unsigned byte = (unsigned)(k * 256) + (((unsigned)(d4 * 2)) ^ (((unsigned)(k & 7)) << 4));
        *(uint2*)((char*)ldsB + byte) = make_uint2(lo, hi);
      }
    }
    __syncthreads();

    f32x4 acc[8];
#pragma unroll
    for (int t = 0; t < 8; ++t) acc[t] = (f32x4){0.f, 0.f, 0.f, 0.f};
#pragma unroll
    for (int t = 0; t < 8; ++t) {
      const unsigned rowbase = (unsigned)((t * 16 + l15) * 256);
#pragma unroll
      for (int s = 0; s < 4; ++s) {
        bf16x8 bfr = *(const bf16x8*)((const char*)ldsB +
                       rowbase + (((unsigned)(s * 64 + l4 * 16)) ^ swz));
        acc[t] = __builtin_amdgcn_mfma_f32_16x16x32_bf16(afr[s], bfr, acc[t], 0, 0, 0);
      }
    }
    // scores + per-lane running argmax
#pragma unroll
    for (int t = 0; t < 8; ++t) {
      const float rc = rcp[kc + t * 16];
      const int cand = (kc >> 4) + t;
      const float g0 = gp0[kc + t * 16];
      const float g1 = gp1[kc + t * 16];
      const float g2 = gp2[kc + t * 16];
      const float g3 = gp3[kc + t * 16];
      float sc;
      sc = fmaf(acc[t][0], rc, g0); if (sc > bs0) { bs0 = sc; bk0 = cand; ba0 = acc[t][0]; }
      sc = fmaf(acc[t][1], rc, g1); if (sc > bs1) { bs1 = sc; bk1 = cand; ba1 = acc[t][1]; }
      sc = fmaf(acc[t][2], rc, g2); if (sc > bs2) { bs2 = sc; bk2 = cand; ba2 = acc[t][2]; }
      sc = fmaf(acc[t][3], rc, g3); if (sc > bs3) { bs3 = sc; bk3 = cand; ba3 = acc[t][3]; }
    }
  }

  // --- reconstruct full k, cross-lane argmax over the 16 lanes sharing rows
  int K0 = bk0 * 16 + l15, K1 = bk1 * 16 + l15, K2 = bk2 * 16 + l15, K3 = bk3 * 16 + l15;
#pragma unroll
  for (int m = 1; m <= 8; m <<= 1) {
    float os; int ok; float oa;
    os = __shfl_xor(bs0, m); ok = __shfl_xor(K0, m); oa = __shfl_xor(ba0, m);
    if (os > bs0 || (os == bs0 && ok < K0)) { bs0 = os; K0 = ok; ba0 = oa; }
    os = __shfl_xor(bs1, m); ok = __shfl_xor(K1, m); oa = __shfl_xor(ba1, m);
    if (os > bs1 || (os == bs1 && ok < K1)) { bs1 = os; K1 = ok; ba1 = oa; }
    os = __shfl_xor(bs2, m); ok = __shfl_xor(K2, m); oa = __shfl_xor(ba2, m);
    if (os > bs2 || (os == bs2 && ok < K2)) { bs2 = os; K2 = ok; ba2 = oa; }
    os = __shfl_xor(bs3, m); ok = __shfl_xor(K3, m); oa = __shfl_xor(ba3, m);
    if (os > bs3 || (os == bs3 && ok < K3)) { bs3 = os; K3 = ok; ba3 = oa; }
  }

  // --- epilogue: nh = codesT[c][k*][:], loss via ||c||^2 + ||h||^2 - 2*dot
  float lsum = 0.f;
  const float* ctc = codesT + (size_t)c * KCB * DCS;
  float* outbase = out + (size_t)(nb + w * 16) * HDIM + c * DCS;
#define EPI(R, KR, BAR) { \
    const int rowr = l4 * 4 + R; \
    const float hn2r = __shfl(hn2, rowr); \
    const float hnr = sqrtf(hn2r); \
    const float c2 = cn2g[c * KCB + KR]; \
    const float arg = c2 + hn2r - 2.f * (BAR * hnr); \
    const float lr = sqrtf(fmaxf(arg, 0.f)); \
    if (l15 == 0) lsum += lr; \
    const f32x4* cp = (const f32x4*)(ctc + (size_t)KR * DCS) + l15 * 2; \
    f32x4* op = (f32x4*)(outbase + (size_t)rowr * HDIM) + l15 * 2; \
    f32x4 v0 = cp[0]; f32x4 v1 = cp[1]; \
    op[0] = v0; op[1] = v1; }
  EPI(0, K0, ba0)
  EPI(1, K1, ba1)
  EPI(2, K2, ba2)
  EPI(3, K3, ba3)
#undef EPI

  lsum += __shfl_xor(lsum, 16);
  lsum += __shfl_xor(lsum, 32);
  if (l == 0) wloss[w] = lsum;
  __syncthreads();
  if (tid == 0) atomicAdd(loss_slot, (wloss[0] + wloss[1] + wloss[2] + wloss[3]) * 1.2f);
}

extern "C" void kernel_launch(void* const* d_in, const int* in_sizes, int n_in,
                              void* d_out, int out_size, void* d_ws, size_t ws_size,
                              hipStream_t stream) {
  const float* hidden = (const float*)d_in[0];
  const float* codes  = (const float*)d_in[1];
  const float* gumbel = (const float*)d_in[2];
  float* out = (float*)d_out;
  float* codesT = (float*)d_ws;                         // 524288 floats (2 MB)
  float* cn2 = codesT + (size_t)CNB * KCB * DCS;        // 4096 floats
  float* rcn = cn2 + CNB * KCB;                         // 4096 floats
  float* loss_slot = out + (size_t)NROWS * HDIM;

  prep_kernel<<<dim3(8, 8), 256, 0, stream>>>(codes, codesT, cn2, rcn, loss_slot);
  vq_kernel<<<dim3(512, CNB), 256, 0, stream>>>(hidden, gumbel, codesT, cn2, rcn, out, loss_slot);
}

// Round 2
// 225.907 us; speedup vs baseline: 1.3791x; 1.3791x over previous
//
#include <hip/hip_runtime.h>
#include <hip/hip_bf16.h>
#include <stdint.h>

#define NROWS 32768
#define HDIM  1024
#define CNB   8
#define DCS   128
#define KCB   512
#define ROWS_PB 128

typedef short bf16x8 __attribute__((ext_vector_type(8)));
typedef float f32x4 __attribute__((ext_vector_type(4)));

__device__ __forceinline__ unsigned f2bfu(float x) {
  union { float f; unsigned u; } v; v.f = x;
  return (v.u + 0x7fffu + ((v.u >> 16) & 1u)) >> 16;
}
__device__ __forceinline__ float bfu2f(unsigned short b) {
  union { unsigned u; float f; } v; v.u = ((unsigned)b) << 16;
  return v.f;
}
__device__ __forceinline__ void gload_lds16(const void* g, void* l) {
  __builtin_amdgcn_global_load_lds(
      (const __attribute__((address_space(1))) uint32_t*)g,
      (__attribute__((address_space(3))) uint32_t*)l, 16, 0, 0);
}

// ---- prep: codesB[c] = bf16 XOR-swizzled 128KB image (4 chunks x 32KB, gl_lds-ready);
//      cn2[c][k] = ||code||^2; rcn = rsqrt(cn2); zero loss slot.
// image byte for (k,d): (k>>7)*32768 + (k&127)*256 + ((2d) ^ ((k&7)<<4))
__global__ __launch_bounds__(256) void prep_kernel(
    const float* __restrict__ codes, unsigned short* __restrict__ codesB,
    float* __restrict__ cn2, float* __restrict__ rcn, float* __restrict__ loss_slot) {
  const int c = blockIdx.y;
  const int k0 = blockIdx.x * 64;
  const int t = threadIdx.x;
  const int kl = t & 63;
  const int dq = t >> 6;
  const int k = k0 + kl;
  const float* src = codes + (size_t)c * DCS * KCB + k;
  char* dstbase = (char*)codesB + (size_t)c * 131072 + (size_t)(k >> 7) * 32768 + (k & 127) * 256;
  const unsigned swzk = (unsigned)(k & 7) << 4;
  float acc = 0.f;
#pragma unroll
  for (int g = 0; g < 4; ++g) {
    unsigned short pk[8];
#pragma unroll
    for (int j = 0; j < 8; ++j) {
      int d = dq * 32 + g * 8 + j;
      float v = src[(size_t)d * KCB];
      acc += v * v;
      pk[j] = (unsigned short)f2bfu(v);
    }
    unsigned d2 = (unsigned)((dq * 32 + g * 8) * 2);
    *(uint4*)(dstbase + (d2 ^ swzk)) = *(const uint4*)pk;
  }
  __shared__ float red[256];
  red[t] = acc;
  __syncthreads();
  if (t < 64) {
    float s = red[t] + red[t + 64] + red[t + 128] + red[t + 192];
    cn2[c * KCB + k0 + t] = s;
    rcn[c * KCB + k0 + t] = rsqrtf(s);
  }
  if (blockIdx.x == 0 && c == 0 && t == 0) *loss_slot = 0.f;
}

// ---- main: 128 rows x 1 codebook per block; 8 waves x 16 rows.
// MFMA: A = codes tile (16k x 32d from LDS), B = h rows -> D[row=code, col=h-row].
__global__ __launch_bounds__(512, 4) void vq_kernel(
    const float* __restrict__ hidden, const float* __restrict__ gumbel,
    const unsigned short* __restrict__ codesB, const float* __restrict__ cn2g,
    const float* __restrict__ rcn, float* __restrict__ out, float* __restrict__ loss_slot) {
  const int c = blockIdx.y;
  const int nb = blockIdx.x * ROWS_PB;
  const int tid = threadIdx.x;
  const int w = tid >> 6;
  const int l = tid & 63;
  const int l15 = l & 15;
  const int l4 = l >> 4;

  __shared__ char ldsB[32768];   // one 32KB chunk: [k_local 128][d 128] bf16, XOR-swizzled
  __shared__ float wloss[8];

  const char* cbase = (const char*)codesB + (size_t)c * 131072;

  // prologue stage of chunk 0 (overlaps h load/norm below)
#pragma unroll
  for (int i = 0; i < 4; ++i)
    gload_lds16(cbase + i * 8192 + tid * 16, ldsB + i * 8192 + w * 1024);

  // --- h rows: per lane row = nb + w*16 + l15, d = s*32 + l4*8 + j
  const int nrow = nb + w * 16 + l15;
  const float* hp = hidden + (size_t)nrow * HDIM + c * DCS + l4 * 8;
  float hv[4][8];
  float hn2 = 0.f;
#pragma unroll
  for (int s = 0; s < 4; ++s) {
    f32x4 p0 = *(const f32x4*)(hp + s * 32);
    f32x4 p1 = *(const f32x4*)(hp + s * 32 + 4);
#pragma unroll
    for (int j = 0; j < 4; ++j) { hv[s][j] = p0[j]; hv[s][4 + j] = p1[j]; }
#pragma unroll
    for (int j = 0; j < 8; ++j) hn2 += hv[s][j] * hv[s][j];
  }
  hn2 += __shfl_xor(hn2, 16);
  hn2 += __shfl_xor(hn2, 32);
  const float hnorm = sqrtf(hn2);
  const float rh = hnorm > 0.f ? 1.0f / hnorm : 0.f;
  bf16x8 afr[4];
#pragma unroll
  for (int s = 0; s < 4; ++s)
#pragma unroll
    for (int j = 0; j < 8; ++j) afr[s][j] = (short)f2bfu(hv[s][j] * rh);

  const float* gbase = gumbel + ((size_t)nrow * CNB + c) * KCB + l4 * 4;
  const float* rbase = rcn + c * KCB + l4 * 4;
  const unsigned swz = (unsigned)(l15 & 7) << 4;

  float bs = -3.4e38f, ba = 0.f;
  int bk = 0;

  __syncthreads();   // chunk 0 staged

#pragma unroll 1
  for (int kc = 0; kc < KCB; kc += 128) {
    // --- MFMA over current chunk
    f32x4 acc[8];
#pragma unroll
    for (int t = 0; t < 8; ++t) acc[t] = (f32x4){0.f, 0.f, 0.f, 0.f};
#pragma unroll
    for (int t = 0; t < 8; ++t) {
      const unsigned rowbase = (unsigned)((t * 16 + l15) * 256);
#pragma unroll
      for (int s = 0; s < 4; ++s) {
        bf16x8 bfr = *(const bf16x8*)(ldsB + rowbase + (((unsigned)(s * 64 + l4 * 16)) ^ swz));
        acc[t] = __builtin_amdgcn_mfma_f32_16x16x32_bf16(bfr, afr[s], acc[t], 0, 0, 0);
      }
    }
    __syncthreads();   // all waves done reading this chunk

    // --- issue next-chunk stage; its latency hides under the score phase
    if (kc + 128 < KCB) {
      const char* src = cbase + (size_t)((kc >> 7) + 1) * 32768;
#pragma unroll
      for (int i = 0; i < 4; ++i)
        gload_lds16(src + i * 8192 + tid * 16, ldsB + i * 8192 + w * 1024);
    }

    // --- scores + per-lane argmax (k = kc + t*16 + l4*4 + r, all for h-row l15)
#pragma unroll
    for (int t = 0; t < 8; ++t) {
      f32x4 g = *(const f32x4*)(gbase + kc + t * 16);
      f32x4 rc = *(const f32x4*)(rbase + kc + t * 16);
#pragma unroll
      for (int r = 0; r < 4; ++r) {
        const int kf = kc + t * 16 + l4 * 4 + r;
        float sc = fmaf(acc[t][r], rc[r], g[r]);
        if (sc > bs) { bs = sc; bk = kf; ba = acc[t][r]; }
      }
    }
    __syncthreads();   // next chunk staged (vmcnt drain at barrier)
  }

  // --- cross-lane argmax over the 4 l4 replicas of each h-row
#pragma unroll
  for (int m = 16; m <= 32; m <<= 1) {
    float os = __shfl_xor(bs, m);
    int ok = __shfl_xor(bk, m);
    float oa = __shfl_xor(ba, m);
    if (os > bs || (os == bs && ok < bk)) { bs = os; bk = ok; ba = oa; }
  }

  // --- epilogue: nh row copy (bf16->f32 from codesB), loss via ||c||^2+||h||^2-2*dot
  const float c2 = cn2g[c * KCB + bk];
  const float arg = c2 + hn2 - 2.f * (ba * hnorm);
  float lsum = (l4 == 0) ? sqrtf(fmaxf(arg, 0.f)) : 0.f;

  const char* cb = cbase + (size_t)(bk >> 7) * 32768 + (bk & 127) * 256;
  const unsigned swzk = (unsigned)(bk & 7) << 4;
  float* op = out + (size_t)nrow * HDIM + c * DCS + l4 * 32;
#pragma unroll
  for (int j = 0; j < 4; ++j) {
    unsigned d2 = (unsigned)((l4 * 32 + j * 8) * 2);
    bf16x8 cv = *(const bf16x8*)(cb + (d2 ^ swzk));
    f32x4 o0, o1;
#pragma unroll
    for (int e = 0; e < 4; ++e) {
      o0[e] = bfu2f((unsigned short)cv[e]);
      o1[e] = bfu2f((unsigned short)cv[4 + e]);
    }
    *(f32x4*)(op + j * 8) = o0;
    *(f32x4*)(op + j * 8 + 4) = o1;
  }

#pragma unroll
  for (int m = 1; m <= 32; m <<= 1) lsum += __shfl_xor(lsum, m);
  if (l == 0) wloss[w] = lsum;
  __syncthreads();
  if (tid == 0) {
    float tot = 0.f;
#pragma unroll
    for (int i = 0; i < 8; ++i) tot += wloss[i];
    atomicAdd(loss_slot, tot * 1.2f);
  }
}

extern "C" void kernel_launch(void* const* d_in, const int* in_sizes, int n_in,
                              void* d_out, int out_size, void* d_ws, size_t ws_size,
                              hipStream_t stream) {
  const float* hidden = (const float*)d_in[0];
  const float* codes  = (const float*)d_in[1];
  const float* gumbel = (const float*)d_in[2];
  float* out = (float*)d_out;
  unsigned short* codesB = (unsigned short*)d_ws;          // 1 MB (8 x 128KB images)
  float* cn2 = (float*)((char*)d_ws + (size_t)CNB * 131072);  // 16 KB
  float* rcn = cn2 + CNB * KCB;                            // 16 KB
  float* loss_slot = out + (size_t)NROWS * HDIM;

  prep_kernel<<<dim3(8, CNB), 256, 0, stream>>>(codes, codesB, cn2, rcn, loss_slot);
  vq_kernel<<<dim3(NROWS / ROWS_PB, CNB), 512, 0, stream>>>(hidden, gumbel, codesB, cn2, rcn, out, loss_slot);
}